// Round 6
// baseline (241.703 us; speedup 1.0000x reference)
//
#include <hip/hip_runtime.h>
#include <hip/hip_bf16.h>
#include <stdint.h>

#define B_ROWS 1024
#define DIM    512
#define C_CLS  100000
#define C_PAD  100352          // 8 XCDs * 49 ntiles * 256
#define NT     392             // C_PAD / 256
#define NT_PER_XCD 49
#define MT     4               // B_ROWS / 256
#define NPAD   (C_PAD - C_CLS) // 352 pad cols, logit 0

using f32x4  = __attribute__((ext_vector_type(4))) float;
using bf16x8 = __attribute__((ext_vector_type(8))) short;   // 8 bf16 (4 VGPRs)

#define AS1(p) ((const __attribute__((address_space(1))) uint32_t*)(p))
#define AS3(p) ((__attribute__((address_space(3))) uint32_t*)(p))
#define SBAR()   __builtin_amdgcn_s_barrier()
#define SCHED0() __builtin_amdgcn_sched_barrier(0)
#define PRIO1()  __builtin_amdgcn_s_setprio(1)
#define PRIO0()  __builtin_amdgcn_s_setprio(0)
#define LGKM0()  asm volatile("s_waitcnt lgkmcnt(0)" ::: "memory")
#define VMCNT0() asm volatile("s_waitcnt vmcnt(0)" ::: "memory")
#define VMCNT6() asm volatile("s_waitcnt vmcnt(6)" ::: "memory")

static __device__ __forceinline__ float bf2f(uint32_t u) { return __uint_as_float(u << 16); }
static __device__ __forceinline__ uint32_t f2bf(float f) {
    uint32_t u = __float_as_uint(f);
    u += 0x7fffu + ((u >> 16) & 1u);          // round-to-nearest-even
    return u >> 16;
}

// ---------- pass 1: per-row L2 normalize (one wave per row), f32 -> bf16; pad rows zeroed
__global__ __launch_bounds__(256) void normalize_rows(
    const float* __restrict__ src, uint16_t* __restrict__ dst, int nvalid, int ntotal)
{
    const int row  = blockIdx.x * 4 + (threadIdx.x >> 6);
    const int lane = threadIdx.x & 63;
    if (row >= ntotal) return;
    uint4* d4 = reinterpret_cast<uint4*>(dst + (size_t)row * DIM);
    if (row >= nvalid) { d4[lane] = make_uint4(0u, 0u, 0u, 0u); return; }
    const float4* s4 = reinterpret_cast<const float4*>(src + (size_t)row * DIM);
    const float4 a = s4[lane * 2], b = s4[lane * 2 + 1];
    float ss = a.x*a.x + a.y*a.y + a.z*a.z + a.w*a.w
             + b.x*b.x + b.y*b.y + b.z*b.z + b.w*b.w;
    #pragma unroll
    for (int k = 1; k < 64; k <<= 1) ss += __shfl_xor(ss, k);
    const float inv = 1.0f / fmaxf(sqrtf(ss), 1e-12f);
    uint4 o;
    o.x = f2bf(a.x*inv) | (f2bf(a.y*inv) << 16);
    o.y = f2bf(a.z*inv) | (f2bf(a.w*inv) << 16);
    o.z = f2bf(b.x*inv) | (f2bf(b.y*inv) << 16);
    o.w = f2bf(b.z*inv) | (f2bf(b.w*inv) << 16);
    d4[lane] = o;
}

// ---------- pass 2: 256x256 bf16 MFMA; r4-proven vmcnt skeleton + lookahead reads,
//            compiler auto-waits gate MFMA operands; fixed-shift sumexp partials
__global__ __launch_bounds__(512, 2) void gemm_lse(
    const uint16_t* __restrict__ A,   // [B_ROWS][DIM]
    const uint16_t* __restrict__ W,   // [C_PAD][DIM]  (pad rows zero)
    float* __restrict__ ps)           // [NT][B_ROWS]
{
    // [buf][region: A0(rows0-127), A1, B0(cols0-127), B1][128*64 bf16], 128 KiB
    __shared__ __align__(16) uint16_t lds[2][4][128 * 64];

    const int tid  = threadIdx.x;
    const int lane = tid & 63;
    const int wid  = tid >> 6;       // 8 waves: 2M x 4N
    const int wr   = wid >> 2;       // 0..1  (128 rows each)
    const int wc   = wid & 3;        // 0..3  (64 cols each)

    const int b     = blockIdx.x;
    const int xcd   = b & 7;
    const int j     = b >> 3;        // 0..195 within XCD
    const int ntile = xcd * NT_PER_XCD + (j >> 2);
    const int mtile = j & 3;

    const uint16_t* Abase = A + (size_t)mtile * 256 * DIM;
    const uint16_t* Bbase = W + (size_t)ntile * 256 * DIM;

    // staging: half-tile = 128 rows x 64 k = 16KB; 2 gload_lds(16B)/thread
    const int r0 = tid >> 3;
    const int us = (tid & 7) ^ (r0 & 7);      // pre-swizzled source unit (rule #21)
    const int r1 = r0 + 64;

    auto stage = [&](int kt, int h) {
        const uint16_t* src = ((h < 2) ? Abase : Bbase)
                            + (size_t)((h & 1) * 128) * DIM + kt * 64;
        uint16_t* dst = &lds[kt & 1][h][0];
        __builtin_amdgcn_global_load_lds(AS1(src + (size_t)r0 * DIM + us * 8),
                                         AS3(dst + tid * 8), 16, 0, 0);
        __builtin_amdgcn_global_load_lds(AS1(src + (size_t)r1 * DIM + us * 8),
                                         AS3(dst + (tid + 512) * 8), 16, 0, 0);
    };

    const int l15 = lane & 15;
    const int uhi = lane >> 4;
    const int ux  = lane & 7;

    bf16x8 aF03[4][2], aF47[4][2], bF01[2][2], bF23[2][2];
    f32x4 acc[8][4] = {};

    auto ldA = [&](int buf, int mi, int ks) {
        const int row  = mi * 16 + l15;
        const int unit = ((ks << 2) | uhi) ^ ux;
        return *reinterpret_cast<const bf16x8*>(&lds[buf][wr][row * 64 + unit * 8]);
    };
    auto ldB = [&](int buf, int ni, int ks) {
        const int row  = (wc & 1) * 64 + ni * 16 + l15;
        const int unit = ((ks << 2) | uhi) ^ ux;
        return *reinterpret_cast<const bf16x8*>(&lds[buf][2 + (wc >> 1)][row * 64 + unit * 8]);
    };
    auto rdA03 = [&](int buf) {
        #pragma unroll
        for (int mi = 0; mi < 4; ++mi) { aF03[mi][0] = ldA(buf, mi, 0); aF03[mi][1] = ldA(buf, mi, 1); }
    };
    auto rdA47 = [&](int buf) {
        #pragma unroll
        for (int mi = 0; mi < 4; ++mi) { aF47[mi][0] = ldA(buf, mi + 4, 0); aF47[mi][1] = ldA(buf, mi + 4, 1); }
    };
    auto rdB01 = [&](int buf) {
        #pragma unroll
        for (int ni = 0; ni < 2; ++ni) { bF01[ni][0] = ldB(buf, ni, 0); bF01[ni][1] = ldB(buf, ni, 1); }
    };
    auto rdB23 = [&](int buf) {
        #pragma unroll
        for (int ni = 0; ni < 2; ++ni) { bF23[ni][0] = ldB(buf, ni + 2, 0); bF23[ni][1] = ldB(buf, ni + 2, 1); }
    };

#define QUAD(AF, BF, MH, NH) { PRIO1(); \
    _Pragma("unroll") for (int m2 = 0; m2 < 4; ++m2) \
    _Pragma("unroll") for (int n2 = 0; n2 < 2; ++n2) \
    _Pragma("unroll") for (int ks = 0; ks < 2; ++ks) \
        acc[(MH)*4+m2][(NH)*2+n2] = __builtin_amdgcn_mfma_f32_16x16x32_bf16( \
            AF[m2][ks], BF[n2][ks], acc[(MH)*4+m2][(NH)*2+n2], 0, 0, 0); \
    PRIO0(); }

    // prologue: kt0 all + kt1 HT0,1,2 (14 loads); VMCNT6 -> kt0 landed; lookahead reads
    stage(0,0); stage(0,1); stage(0,2); stage(0,3);
    stage(1,0); stage(1,1); stage(1,2);
    VMCNT6(); SCHED0(); SBAR();
    rdB01(0); rdA03(0); SCHED0();

    // steady: kt=t in buf0 (h0-h3), kt+1 in buf1 (h4-h7)
    #pragma unroll 1
    for (int t = 0; t < 6; t += 2) {
        // h0
        rdB23(0); rdA47(0); SCHED0(); stage(t+1, 3); SCHED0(); SBAR(); SCHED0();
        QUAD(aF03, bF01, 0, 0); SCHED0(); SBAR();
        // h1  (LGKM0 certifies h0 reads retired before h2+ stages overwrite kt regions)
        QUAD(aF03, bF23, 0, 1); SCHED0(); LGKM0(); SCHED0(); SBAR();
        // h2
        stage(t+2, 2); stage(t+2, 3); SCHED0(); SBAR(); SCHED0();
        QUAD(aF47, bF01, 1, 0); SCHED0(); SBAR();
        // h3  (VMCNT6+SBAR certifies kt+1 fully landed -> lookahead reads)
        stage(t+2, 0); VMCNT6(); SCHED0(); SBAR(); SCHED0();
        rdB01(1); rdA03(1); SCHED0();
        QUAD(aF47, bF23, 1, 1); SCHED0(); SBAR();
        // h4
        rdB23(1); rdA47(1); SCHED0(); stage(t+2, 1); SCHED0(); SBAR(); SCHED0();
        QUAD(aF03, bF01, 0, 0); SCHED0(); SBAR();
        // h5
        QUAD(aF03, bF23, 0, 1); SCHED0(); LGKM0(); SCHED0(); SBAR();
        // h6
        stage(t+3, 0); stage(t+3, 1); SCHED0(); SBAR(); SCHED0();
        QUAD(aF47, bF01, 1, 0); SCHED0(); SBAR();
        // h7
        stage(t+3, 2); VMCNT6(); SCHED0(); SBAR(); SCHED0();
        rdB01(0); rdA03(0); SCHED0();
        QUAD(aF47, bF23, 1, 1); SCHED0(); SBAR();
    }

    // tail: kt6 (buf0), kt7 (buf1); only kt7.HT3 left to stage
    rdB23(0); rdA47(0); SCHED0(); stage(7, 3); SCHED0(); SBAR(); SCHED0();
    QUAD(aF03, bF01, 0, 0); SCHED0(); SBAR();
    QUAD(aF03, bF23, 0, 1); SCHED0(); LGKM0(); SCHED0(); SBAR();
    QUAD(aF47, bF01, 1, 0); SCHED0(); SBAR();
    VMCNT0(); SCHED0(); SBAR(); SCHED0();
    rdB01(1); rdA03(1); SCHED0();
    QUAD(aF47, bF23, 1, 1); SCHED0(); SBAR();
    rdB23(1); rdA47(1); SCHED0(); SBAR(); SCHED0();
    QUAD(aF03, bF01, 0, 0); SCHED0(); SBAR();
    QUAD(aF03, bF23, 0, 1); SCHED0(); SBAR();
    QUAD(aF47, bF01, 1, 0); SCHED0();
    QUAD(aF47, bF23, 1, 1);

    // epilogue: logits = 64*cos in [-64,64]; fixed shift 64 -> sum exp(logit-64)
    __syncthreads();                               // full drain; reuse LDS as red buffer
    float* red = reinterpret_cast<float*>(&lds[0][0][0]);   // [256 rows][4 wc]
    #pragma unroll
    for (int mi = 0; mi < 8; ++mi) {
        #pragma unroll
        for (int r = 0; r < 4; ++r) {
            float s = __expf(fmaf(acc[mi][0][r], 64.0f, -64.0f))
                    + __expf(fmaf(acc[mi][1][r], 64.0f, -64.0f))
                    + __expf(fmaf(acc[mi][2][r], 64.0f, -64.0f))
                    + __expf(fmaf(acc[mi][3][r], 64.0f, -64.0f));
            #pragma unroll
            for (int k = 1; k < 16; k <<= 1) s += __shfl_xor(s, k);
            if (l15 == 0) red[(wr * 128 + mi * 16 + uhi * 4 + r) * 4 + wc] = s;
        }
    }
    __syncthreads();
    if (tid < 256)
        ps[(size_t)ntile * B_ROWS + mtile * 256 + tid] =
            red[tid*4+0] + red[tid*4+1] + red[tid*4+2] + red[tid*4+3];
}

// ---------- pass 3: per-row sum of partials + exact margin/pad correction
__global__ __launch_bounds__(256) void finalize(
    const float* __restrict__ ps,
    const uint16_t* __restrict__ fb, const uint16_t* __restrict__ wb,
    const int* __restrict__ labels, float* __restrict__ row_loss)
{
    const int row = blockIdx.x;
    const int t   = threadIdx.x;      // 256
    const int lab = labels[row];

    // target cosine in f32 from the same bf16 vectors the GEMM used
    uint32_t fa = reinterpret_cast<const uint32_t*>(fb + (size_t)row * DIM)[t];
    uint32_t wa = reinterpret_cast<const uint32_t*>(wb + (size_t)lab * DIM)[t];
    float d = bf2f(fa & 0xffffu) * bf2f(wa & 0xffffu) + bf2f(fa >> 16) * bf2f(wa >> 16);
    #pragma unroll
    for (int k = 1; k < 64; k <<= 1) d += __shfl_xor(d, k);

    float s = 0.0f;
    for (int i = t; i < NT; i += 256) s += ps[(size_t)i * B_ROWS + row];
    #pragma unroll
    for (int k = 1; k < 64; k <<= 1) s += __shfl_xor(s, k);

    __shared__ float sd[4], ssm[4];
    if ((t & 63) == 0) { sd[t >> 6] = d; ssm[t >> 6] = s; }
    __syncthreads();
    if (t == 0) {
        const float dt = sd[0] + sd[1] + sd[2] + sd[3];
        float S = ssm[0] + ssm[1] + ssm[2] + ssm[3];
        const float lt = 64.0f * dt;
        // swap unmargined target term for margined one; remove pad columns (logit 0)
        S += expf(lt - 96.0f) - expf(lt - 64.0f) - (float)NPAD * expf(-64.0f);
        row_loss[row] = 64.0f + logf(S) - (lt - 32.0f);
    }
}

// ---------- pass 4: mean over rows
__global__ __launch_bounds__(256) void mean_k(const float* __restrict__ rl, float* __restrict__ out)
{
    const int t = threadIdx.x;
    float s = 0.0f;
    for (int i = t; i < B_ROWS; i += 256) s += rl[i];
    #pragma unroll
    for (int k = 1; k < 64; k <<= 1) s += __shfl_xor(s, k);
    __shared__ float r4[4];
    if ((t & 63) == 0) r4[t >> 6] = s;
    __syncthreads();
    if (t == 0) out[0] = (r4[0] + r4[1] + r4[2] + r4[3]) * (1.0f / B_ROWS);
}

extern "C" void kernel_launch(void* const* d_in, const int* in_sizes, int n_in,
                              void* d_out, int out_size, void* d_ws, size_t ws_size,
                              hipStream_t stream)
{
    const float* features = (const float*)d_in[0];
    const int*   labels   = (const int*)d_in[1];
    const float* weight   = (const float*)d_in[2];

    char* ws = (char*)d_ws;
    uint16_t* wb = (uint16_t*)ws;                                        // C_PAD * DIM bf16
    uint16_t* fb = (uint16_t*)(ws + (size_t)C_PAD * DIM * 2);            // B_ROWS * DIM bf16
    float*    psum = (float*)(ws + (size_t)C_PAD * DIM * 2 + (size_t)B_ROWS * DIM * 2);
    float*    rl = psum + (size_t)NT * B_ROWS;

    normalize_rows<<<C_PAD / 4, 256, 0, stream>>>(weight, wb, C_CLS, C_PAD);
    normalize_rows<<<B_ROWS / 4, 256, 0, stream>>>(features, fb, B_ROWS, B_ROWS);
    gemm_lse<<<NT * MT, 512, 0, stream>>>(fb, wb, psum);
    finalize<<<B_ROWS, 256, 0, stream>>>(psum, fb, wb, labels, rl);
    mean_k<<<1, 256, 0, stream>>>(rl, (float*)d_out);
}

// Round 7
// 241.129 us; speedup vs baseline: 1.0024x; 1.0024x over previous
//
#include <hip/hip_runtime.h>
#include <hip/hip_bf16.h>
#include <stdint.h>

#define B_ROWS 1024
#define DIM    512
#define C_CLS  100000
#define C_PAD  100352          // 8 XCDs * 49 ntiles * 256
#define NT     392             // C_PAD / 256
#define NT_PER_XCD 49
#define MT     4               // B_ROWS / 256
#define NPAD   (C_PAD - C_CLS) // 352 pad cols, logit 0

using f32x4  = __attribute__((ext_vector_type(4))) float;
using bf16x8 = __attribute__((ext_vector_type(8))) short;   // 8 bf16 (4 VGPRs)

#define AS1(p) ((const __attribute__((address_space(1))) uint32_t*)(p))
#define AS3(p) ((__attribute__((address_space(3))) uint32_t*)(p))
#define SBAR()   __builtin_amdgcn_s_barrier()
#define SCHED0() __builtin_amdgcn_sched_barrier(0)
#define PRIO1()  __builtin_amdgcn_s_setprio(1)
#define PRIO0()  __builtin_amdgcn_s_setprio(0)
#define LGKM0()  asm volatile("s_waitcnt lgkmcnt(0)" ::: "memory")
#define VMCNT0() asm volatile("s_waitcnt vmcnt(0)" ::: "memory")
#define VMCNT6() asm volatile("s_waitcnt vmcnt(6)" ::: "memory")

static __device__ __forceinline__ float bf2f(uint32_t u) { return __uint_as_float(u << 16); }
static __device__ __forceinline__ uint32_t f2bf(float f) {
    uint32_t u = __float_as_uint(f);
    u += 0x7fffu + ((u >> 16) & 1u);          // round-to-nearest-even
    return u >> 16;
}

// ---------- pass 1: per-row L2 normalize (one wave per row), f32 -> bf16; pad rows zeroed
__global__ __launch_bounds__(256) void normalize_rows(
    const float* __restrict__ src, uint16_t* __restrict__ dst, int nvalid, int ntotal)
{
    const int row  = blockIdx.x * 4 + (threadIdx.x >> 6);
    const int lane = threadIdx.x & 63;
    if (row >= ntotal) return;
    uint4* d4 = reinterpret_cast<uint4*>(dst + (size_t)row * DIM);
    if (row >= nvalid) { d4[lane] = make_uint4(0u, 0u, 0u, 0u); return; }
    const float4* s4 = reinterpret_cast<const float4*>(src + (size_t)row * DIM);
    const float4 a = s4[lane * 2], b = s4[lane * 2 + 1];
    float ss = a.x*a.x + a.y*a.y + a.z*a.z + a.w*a.w
             + b.x*b.x + b.y*b.y + b.z*b.z + b.w*b.w;
    #pragma unroll
    for (int k = 1; k < 64; k <<= 1) ss += __shfl_xor(ss, k);
    const float inv = 1.0f / fmaxf(sqrtf(ss), 1e-12f);
    uint4 o;
    o.x = f2bf(a.x*inv) | (f2bf(a.y*inv) << 16);
    o.y = f2bf(a.z*inv) | (f2bf(a.w*inv) << 16);
    o.z = f2bf(b.x*inv) | (f2bf(b.y*inv) << 16);
    o.w = f2bf(b.z*inv) | (f2bf(b.w*inv) << 16);
    d4[lane] = o;
}

// ---------- pass 2: 256x256 bf16 MFMA; r4-proven vmcnt skeleton + lookahead reads,
//            compiler auto-waits gate MFMA operands; fixed-shift sumexp partials
//            __launch_bounds__(512,1): LDS (128KiB) caps at 1 block/CU anyway; give
//            the allocator the full 256-VGPR budget -> no scratch spill.
__global__ __launch_bounds__(512, 1) void gemm_lse(
    const uint16_t* __restrict__ A,   // [B_ROWS][DIM]
    const uint16_t* __restrict__ W,   // [C_PAD][DIM]  (pad rows zero)
    float* __restrict__ ps)           // [NT][B_ROWS]
{
    // [buf][region: A0(rows0-127), A1, B0(cols0-127), B1][128*64 bf16], 128 KiB
    __shared__ __align__(16) uint16_t lds[2][4][128 * 64];

    const int tid  = threadIdx.x;
    const int lane = tid & 63;
    const int wid  = tid >> 6;       // 8 waves: 2M x 4N
    const int wr   = wid >> 2;       // 0..1  (128 rows each)
    const int wc   = wid & 3;        // 0..3  (64 cols each)

    const int b     = blockIdx.x;
    const int xcd   = b & 7;
    const int j     = b >> 3;        // 0..195 within XCD
    const int ntile = xcd * NT_PER_XCD + (j >> 2);
    const int mtile = j & 3;

    const uint16_t* Abase = A + (size_t)mtile * 256 * DIM;
    const uint16_t* Bbase = W + (size_t)ntile * 256 * DIM;

    // staging: half-tile = 128 rows x 64 k = 16KB; 2 gload_lds(16B)/thread
    const int r0 = tid >> 3;
    const int us = (tid & 7) ^ (r0 & 7);      // pre-swizzled source unit (rule #21)
    const int r1 = r0 + 64;

    auto stage = [&](int kt, int h) {
        const uint16_t* src = ((h < 2) ? Abase : Bbase)
                            + (size_t)((h & 1) * 128) * DIM + kt * 64;
        uint16_t* dst = &lds[kt & 1][h][0];
        __builtin_amdgcn_global_load_lds(AS1(src + (size_t)r0 * DIM + us * 8),
                                         AS3(dst + tid * 8), 16, 0, 0);
        __builtin_amdgcn_global_load_lds(AS1(src + (size_t)r1 * DIM + us * 8),
                                         AS3(dst + (tid + 512) * 8), 16, 0, 0);
    };

    const int l15 = lane & 15;
    const int uhi = lane >> 4;
    const int ux  = lane & 7;

    bf16x8 aF03[4][2], aF47[4][2], bF01[2][2], bF23[2][2];
    f32x4 acc[8][4] = {};

    auto ldA = [&](int buf, int mi, int ks) {
        const int row  = mi * 16 + l15;
        const int unit = ((ks << 2) | uhi) ^ ux;
        return *reinterpret_cast<const bf16x8*>(&lds[buf][wr][row * 64 + unit * 8]);
    };
    auto ldB = [&](int buf, int ni, int ks) {
        const int row  = (wc & 1) * 64 + ni * 16 + l15;
        const int unit = ((ks << 2) | uhi) ^ ux;
        return *reinterpret_cast<const bf16x8*>(&lds[buf][2 + (wc >> 1)][row * 64 + unit * 8]);
    };
    auto rdA03 = [&](int buf) {
        #pragma unroll
        for (int mi = 0; mi < 4; ++mi) { aF03[mi][0] = ldA(buf, mi, 0); aF03[mi][1] = ldA(buf, mi, 1); }
    };
    auto rdA47 = [&](int buf) {
        #pragma unroll
        for (int mi = 0; mi < 4; ++mi) { aF47[mi][0] = ldA(buf, mi + 4, 0); aF47[mi][1] = ldA(buf, mi + 4, 1); }
    };
    auto rdB01 = [&](int buf) {
        #pragma unroll
        for (int ni = 0; ni < 2; ++ni) { bF01[ni][0] = ldB(buf, ni, 0); bF01[ni][1] = ldB(buf, ni, 1); }
    };
    auto rdB23 = [&](int buf) {
        #pragma unroll
        for (int ni = 0; ni < 2; ++ni) { bF23[ni][0] = ldB(buf, ni + 2, 0); bF23[ni][1] = ldB(buf, ni + 2, 1); }
    };

#define QUAD(AF, BF, MH, NH) { PRIO1(); \
    _Pragma("unroll") for (int m2 = 0; m2 < 4; ++m2) \
    _Pragma("unroll") for (int n2 = 0; n2 < 2; ++n2) \
    _Pragma("unroll") for (int ks = 0; ks < 2; ++ks) \
        acc[(MH)*4+m2][(NH)*2+n2] = __builtin_amdgcn_mfma_f32_16x16x32_bf16( \
            AF[m2][ks], BF[n2][ks], acc[(MH)*4+m2][(NH)*2+n2], 0, 0, 0); \
    PRIO0(); }

    // prologue: kt0 all + kt1 HT0,1,2 (14 loads); VMCNT6 -> kt0 landed; lookahead reads
    stage(0,0); stage(0,1); stage(0,2); stage(0,3);
    stage(1,0); stage(1,1); stage(1,2);
    VMCNT6(); SCHED0(); SBAR();
    rdB01(0); rdA03(0); SCHED0();

    // steady: kt=t in buf0 (h0-h3), kt+1 in buf1 (h4-h7)
    #pragma unroll 1
    for (int t = 0; t < 6; t += 2) {
        // h0
        rdB23(0); rdA47(0); SCHED0(); stage(t+1, 3); SCHED0(); SBAR(); SCHED0();
        QUAD(aF03, bF01, 0, 0); SCHED0(); SBAR();
        // h1  (LGKM0 certifies h0 reads retired before h2+ stages overwrite kt regions)
        QUAD(aF03, bF23, 0, 1); SCHED0(); LGKM0(); SCHED0(); SBAR();
        // h2
        stage(t+2, 2); stage(t+2, 3); SCHED0(); SBAR(); SCHED0();
        QUAD(aF47, bF01, 1, 0); SCHED0(); SBAR();
        // h3  (VMCNT6+SBAR certifies kt+1 fully landed -> lookahead reads)
        stage(t+2, 0); VMCNT6(); SCHED0(); SBAR(); SCHED0();
        rdB01(1); rdA03(1); SCHED0();
        QUAD(aF47, bF23, 1, 1); SCHED0(); SBAR();
        // h4
        rdB23(1); rdA47(1); SCHED0(); stage(t+2, 1); SCHED0(); SBAR(); SCHED0();
        QUAD(aF03, bF01, 0, 0); SCHED0(); SBAR();
        // h5
        QUAD(aF03, bF23, 0, 1); SCHED0(); LGKM0(); SCHED0(); SBAR();
        // h6
        stage(t+3, 0); stage(t+3, 1); SCHED0(); SBAR(); SCHED0();
        QUAD(aF47, bF01, 1, 0); SCHED0(); SBAR();
        // h7
        stage(t+3, 2); VMCNT6(); SCHED0(); SBAR(); SCHED0();
        rdB01(0); rdA03(0); SCHED0();
        QUAD(aF47, bF23, 1, 1); SCHED0(); SBAR();
    }

    // tail: kt6 (buf0), kt7 (buf1); only kt7.HT3 left to stage
    rdB23(0); rdA47(0); SCHED0(); stage(7, 3); SCHED0(); SBAR(); SCHED0();
    QUAD(aF03, bF01, 0, 0); SCHED0(); SBAR();
    QUAD(aF03, bF23, 0, 1); SCHED0(); LGKM0(); SCHED0(); SBAR();
    QUAD(aF47, bF01, 1, 0); SCHED0(); SBAR();
    VMCNT0(); SCHED0(); SBAR(); SCHED0();
    rdB01(1); rdA03(1); SCHED0();
    QUAD(aF47, bF23, 1, 1); SCHED0(); SBAR();
    rdB23(1); rdA47(1); SCHED0(); SBAR(); SCHED0();
    QUAD(aF03, bF01, 0, 0); SCHED0(); SBAR();
    QUAD(aF03, bF23, 0, 1); SCHED0(); SBAR();
    QUAD(aF47, bF01, 1, 0); SCHED0();
    QUAD(aF47, bF23, 1, 1);

    // epilogue: logits = 64*cos in [-64,64]; fixed shift 64 -> sum exp(logit-64)
    __syncthreads();                               // full drain; reuse LDS as red buffer
    float* red = reinterpret_cast<float*>(&lds[0][0][0]);   // [256 rows][4 wc]
    #pragma unroll
    for (int mi = 0; mi < 8; ++mi) {
        #pragma unroll
        for (int r = 0; r < 4; ++r) {
            float s = __expf(fmaf(acc[mi][0][r], 64.0f, -64.0f))
                    + __expf(fmaf(acc[mi][1][r], 64.0f, -64.0f))
                    + __expf(fmaf(acc[mi][2][r], 64.0f, -64.0f))
                    + __expf(fmaf(acc[mi][3][r], 64.0f, -64.0f));
            #pragma unroll
            for (int k = 1; k < 16; k <<= 1) s += __shfl_xor(s, k);
            if (l15 == 0) red[(wr * 128 + mi * 16 + uhi * 4 + r) * 4 + wc] = s;
        }
    }
    __syncthreads();
    if (tid < 256)
        ps[(size_t)ntile * B_ROWS + mtile * 256 + tid] =
            red[tid*4+0] + red[tid*4+1] + red[tid*4+2] + red[tid*4+3];
}

// ---------- pass 3: per-row sum of partials + exact margin/pad correction
__global__ __launch_bounds__(256) void finalize(
    const float* __restrict__ ps,
    const uint16_t* __restrict__ fb, const uint16_t* __restrict__ wb,
    const int* __restrict__ labels, float* __restrict__ row_loss)
{
    const int row = blockIdx.x;
    const int t   = threadIdx.x;      // 256
    const int lab = labels[row];

    // target cosine in f32 from the same bf16 vectors the GEMM used
    uint32_t fa = reinterpret_cast<const uint32_t*>(fb + (size_t)row * DIM)[t];
    uint32_t wa = reinterpret_cast<const uint32_t*>(wb + (size_t)lab * DIM)[t];
    float d = bf2f(fa & 0xffffu) * bf2f(wa & 0xffffu) + bf2f(fa >> 16) * bf2f(wa >> 16);
    #pragma unroll
    for (int k = 1; k < 64; k <<= 1) d += __shfl_xor(d, k);

    float s = 0.0f;
    for (int i = t; i < NT; i += 256) s += ps[(size_t)i * B_ROWS + row];
    #pragma unroll
    for (int k = 1; k < 64; k <<= 1) s += __shfl_xor(s, k);

    __shared__ float sd[4], ssm[4];
    if ((t & 63) == 0) { sd[t >> 6] = d; ssm[t >> 6] = s; }
    __syncthreads();
    if (t == 0) {
        const float dt = sd[0] + sd[1] + sd[2] + sd[3];
        float S = ssm[0] + ssm[1] + ssm[2] + ssm[3];
        const float lt = 64.0f * dt;
        // swap unmargined target term for margined one; remove pad columns (logit 0)
        S += expf(lt - 96.0f) - expf(lt - 64.0f) - (float)NPAD * expf(-64.0f);
        row_loss[row] = 64.0f + logf(S) - (lt - 32.0f);
    }
}

// ---------- pass 4: mean over rows
__global__ __launch_bounds__(256) void mean_k(const float* __restrict__ rl, float* __restrict__ out)
{
    const int t = threadIdx.x;
    float s = 0.0f;
    for (int i = t; i < B_ROWS; i += 256) s += rl[i];
    #pragma unroll
    for (int k = 1; k < 64; k <<= 1) s += __shfl_xor(s, k);
    __shared__ float r4[4];
    if ((t & 63) == 0) r4[t >> 6] = s;
    __syncthreads();
    if (t == 0) out[0] = (r4[0] + r4[1] + r4[2] + r4[3]) * (1.0f / B_ROWS);
}

extern "C" void kernel_launch(void* const* d_in, const int* in_sizes, int n_in,
                              void* d_out, int out_size, void* d_ws, size_t ws_size,
                              hipStream_t stream)
{
    const float* features = (const float*)d_in[0];
    const int*   labels   = (const int*)d_in[1];
    const float* weight   = (const float*)d_in[2];

    char* ws = (char*)d_ws;
    uint16_t* wb = (uint16_t*)ws;                                        // C_PAD * DIM bf16
    uint16_t* fb = (uint16_t*)(ws + (size_t)C_PAD * DIM * 2);            // B_ROWS * DIM bf16
    float*    psum = (float*)(ws + (size_t)C_PAD * DIM * 2 + (size_t)B_ROWS * DIM * 2);
    float*    rl = psum + (size_t)NT * B_ROWS;

    normalize_rows<<<C_PAD / 4, 256, 0, stream>>>(weight, wb, C_CLS, C_PAD);
    normalize_rows<<<B_ROWS / 4, 256, 0, stream>>>(features, fb, B_ROWS, B_ROWS);
    gemm_lse<<<NT * MT, 512, 0, stream>>>(fb, wb, psum);
    finalize<<<B_ROWS, 256, 0, stream>>>(psum, fb, wb, labels, rl);
    mean_k<<<1, 256, 0, stream>>>(rl, (float*)d_out);
}

// Round 8
// 190.026 us; speedup vs baseline: 1.2719x; 1.2689x over previous
//
#include <hip/hip_runtime.h>
#include <hip/hip_bf16.h>
#include <stdint.h>

#define B_ROWS 1024
#define DIM    512
#define C_CLS  100000
#define C_PAD  100352          // 8 XCDs * 49 ntiles * 256
#define NT     392             // C_PAD / 256
#define NT_PER_XCD 49
#define MT     4               // B_ROWS / 256
#define NPAD   (C_PAD - C_CLS) // 352 pad cols, logit 0

using f32x4  = __attribute__((ext_vector_type(4))) float;
using bf16x8 = __attribute__((ext_vector_type(8))) short;   // 8 bf16 (4 VGPRs)

#define AS1(p) ((const __attribute__((address_space(1))) uint32_t*)(p))
#define AS3(p) ((__attribute__((address_space(3))) uint32_t*)(p))
#define SBAR()   __builtin_amdgcn_s_barrier()
#define SCHED0() __builtin_amdgcn_sched_barrier(0)
#define PRIO1()  __builtin_amdgcn_s_setprio(1)
#define PRIO0()  __builtin_amdgcn_s_setprio(0)
#define LGKM0()  asm volatile("s_waitcnt lgkmcnt(0)" ::: "memory")
#define VMCNT0() asm volatile("s_waitcnt vmcnt(0)" ::: "memory")
#define VMCNT6() asm volatile("s_waitcnt vmcnt(6)" ::: "memory")

static __device__ __forceinline__ float bf2f(uint32_t u) { return __uint_as_float(u << 16); }
static __device__ __forceinline__ uint32_t f2bf(float f) {
    uint32_t u = __float_as_uint(f);
    u += 0x7fffu + ((u >> 16) & 1u);          // round-to-nearest-even
    return u >> 16;
}

// ---------- pass 1: per-row L2 normalize (one wave per row), f32 -> bf16; pad rows zeroed
__global__ __launch_bounds__(256) void normalize_rows(
    const float* __restrict__ src, uint16_t* __restrict__ dst, int nvalid, int ntotal)
{
    const int row  = blockIdx.x * 4 + (threadIdx.x >> 6);
    const int lane = threadIdx.x & 63;
    if (row >= ntotal) return;
    uint4* d4 = reinterpret_cast<uint4*>(dst + (size_t)row * DIM);
    if (row >= nvalid) { d4[lane] = make_uint4(0u, 0u, 0u, 0u); return; }
    const float4* s4 = reinterpret_cast<const float4*>(src + (size_t)row * DIM);
    const float4 a = s4[lane * 2], b = s4[lane * 2 + 1];
    float ss = a.x*a.x + a.y*a.y + a.z*a.z + a.w*a.w
             + b.x*b.x + b.y*b.y + b.z*b.z + b.w*b.w;
    #pragma unroll
    for (int k = 1; k < 64; k <<= 1) ss += __shfl_xor(ss, k);
    const float inv = 1.0f / fmaxf(sqrtf(ss), 1e-12f);
    uint4 o;
    o.x = f2bf(a.x*inv) | (f2bf(a.y*inv) << 16);
    o.y = f2bf(a.z*inv) | (f2bf(a.w*inv) << 16);
    o.z = f2bf(b.x*inv) | (f2bf(b.y*inv) << 16);
    o.w = f2bf(b.z*inv) | (f2bf(b.w*inv) << 16);
    d4[lane] = o;
}

// ---------- pass 2: 256x256 bf16 MFMA; r6-proven barrier/vmcnt skeleton, register-diet
//            fragment schedule (single aF buffer: acc=128 regs/lane, frags must fit 128).
__global__ __launch_bounds__(512) void gemm_lse(
    const uint16_t* __restrict__ A,   // [B_ROWS][DIM]
    const uint16_t* __restrict__ W,   // [C_PAD][DIM]  (pad rows zero)
    float* __restrict__ ps)           // [NT][B_ROWS]
{
    // [buf][region: A0(rows0-127), A1, B0(cols0-127), B1][128*64 bf16], 128 KiB
    __shared__ __align__(16) uint16_t lds[2][4][128 * 64];

    const int tid  = threadIdx.x;
    const int lane = tid & 63;
    const int wid  = tid >> 6;       // 8 waves: 2M x 4N
    const int wr   = wid >> 2;       // 0..1  (128 rows each)
    const int wc   = wid & 3;        // 0..3  (64 cols each)

    const int b     = blockIdx.x;
    const int xcd   = b & 7;
    const int j     = b >> 3;        // 0..195 within XCD
    const int ntile = xcd * NT_PER_XCD + (j >> 2);
    const int mtile = j & 3;

    const uint16_t* Abase = A + (size_t)mtile * 256 * DIM;
    const uint16_t* Bbase = W + (size_t)ntile * 256 * DIM;

    // staging: half-tile = 128 rows x 64 k = 16KB; 2 gload_lds(16B)/thread
    const int r0 = tid >> 3;
    const int us = (tid & 7) ^ (r0 & 7);      // pre-swizzled source unit (rule #21)
    const int r1 = r0 + 64;

    auto stage = [&](int kt, int h) {
        const uint16_t* src = ((h < 2) ? Abase : Bbase)
                            + (size_t)((h & 1) * 128) * DIM + kt * 64;
        uint16_t* dst = &lds[kt & 1][h][0];
        __builtin_amdgcn_global_load_lds(AS1(src + (size_t)r0 * DIM + us * 8),
                                         AS3(dst + tid * 8), 16, 0, 0);
        __builtin_amdgcn_global_load_lds(AS1(src + (size_t)r1 * DIM + us * 8),
                                         AS3(dst + (tid + 512) * 8), 16, 0, 0);
    };

    const int l15 = lane & 15;
    const int uhi = lane >> 4;
    const int ux  = lane & 7;

    bf16x8 aF[4][2], bF01[2][2], bF23[2][2];   // aF time-shared: rows 0-3 then 4-7
    f32x4 acc[8][4] = {};

    auto ldA = [&](int buf, int mi, int ks) {
        const int row  = mi * 16 + l15;
        const int unit = ((ks << 2) | uhi) ^ ux;
        return *reinterpret_cast<const bf16x8*>(&lds[buf][wr][row * 64 + unit * 8]);
    };
    auto ldB = [&](int buf, int ni, int ks) {
        const int row  = (wc & 1) * 64 + ni * 16 + l15;
        const int unit = ((ks << 2) | uhi) ^ ux;
        return *reinterpret_cast<const bf16x8*>(&lds[buf][2 + (wc >> 1)][row * 64 + unit * 8]);
    };
    auto rdA03 = [&](int buf) {
        #pragma unroll
        for (int mi = 0; mi < 4; ++mi) { aF[mi][0] = ldA(buf, mi, 0); aF[mi][1] = ldA(buf, mi, 1); }
    };
    auto rdA47 = [&](int buf) {
        #pragma unroll
        for (int mi = 0; mi < 4; ++mi) { aF[mi][0] = ldA(buf, mi + 4, 0); aF[mi][1] = ldA(buf, mi + 4, 1); }
    };
    auto rdB01 = [&](int buf) {
        #pragma unroll
        for (int ni = 0; ni < 2; ++ni) { bF01[ni][0] = ldB(buf, ni, 0); bF01[ni][1] = ldB(buf, ni, 1); }
    };
    auto rdB23 = [&](int buf) {
        #pragma unroll
        for (int ni = 0; ni < 2; ++ni) { bF23[ni][0] = ldB(buf, ni + 2, 0); bF23[ni][1] = ldB(buf, ni + 2, 1); }
    };

#define QUAD(BF, MH, NH) { PRIO1(); \
    _Pragma("unroll") for (int m2 = 0; m2 < 4; ++m2) \
    _Pragma("unroll") for (int n2 = 0; n2 < 2; ++n2) \
    _Pragma("unroll") for (int ks = 0; ks < 2; ++ks) \
        acc[(MH)*4+m2][(NH)*2+n2] = __builtin_amdgcn_mfma_f32_16x16x32_bf16( \
            aF[m2][ks], BF[n2][ks], acc[(MH)*4+m2][(NH)*2+n2], 0, 0, 0); \
    PRIO0(); }

    // prologue: kt0 all + kt1 HT0,1,2 (14 loads); VMCNT6 -> kt0 landed; pre-read bF01 only
    stage(0,0); stage(0,1); stage(0,2); stage(0,3);
    stage(1,0); stage(1,1); stage(1,2);
    VMCNT6(); SCHED0(); SBAR();
    rdB01(0); SCHED0();

    // steady: kt=t in buf0 (h0-h3), kt+1 in buf1 (h4-h7); stage/wait slots IDENTICAL to r6
    #pragma unroll 1
    for (int t = 0; t < 6; t += 2) {
        // h0
        rdA03(0); rdB23(0); SCHED0(); stage(t+1, 3); SCHED0(); SBAR(); SCHED0();
        QUAD(bF01, 0, 0); SCHED0(); SBAR();
        // h1  (LGKM0 certifies h0 reads retired before h2 stages overwrite buf0 B-regions)
        QUAD(bF23, 0, 1); SCHED0(); LGKM0(); SCHED0();
        rdA47(0); SCHED0(); SBAR();
        // h2  (rdA47 consumed here -> auto-waitcnt; retired before h3's buf0.A0 stage)
        stage(t+2, 2); stage(t+2, 3); SCHED0(); SBAR(); SCHED0();
        QUAD(bF01, 1, 0); SCHED0(); SBAR();
        // h3  (VMCNT6+SBAR certifies buf1 kt+1 fully landed)
        stage(t+2, 0); VMCNT6(); SCHED0(); SBAR(); SCHED0();
        rdB01(1); SCHED0();
        QUAD(bF23, 1, 1); SCHED0(); SBAR();
        // h4
        rdA03(1); rdB23(1); SCHED0(); stage(t+2, 1); SCHED0(); SBAR(); SCHED0();
        QUAD(bF01, 0, 0); SCHED0(); SBAR();
        // h5
        QUAD(bF23, 0, 1); SCHED0(); LGKM0(); SCHED0();
        rdA47(1); SCHED0(); SBAR();
        // h6
        stage(t+3, 0); stage(t+3, 1); SCHED0(); SBAR(); SCHED0();
        QUAD(bF01, 1, 0); SCHED0(); SBAR();
        // h7
        stage(t+3, 2); VMCNT6(); SCHED0(); SBAR(); SCHED0();
        rdB01(0); SCHED0();
        QUAD(bF23, 1, 1); SCHED0(); SBAR();
    }

    // tail: kt6 (buf0), kt7 (buf1); only kt7.HT3 left to stage
    rdA03(0); rdB23(0); SCHED0(); stage(7, 3); SCHED0(); SBAR(); SCHED0();
    QUAD(bF01, 0, 0); SCHED0(); SBAR();
    QUAD(bF23, 0, 1); SCHED0(); LGKM0(); SCHED0();
    rdA47(0); SCHED0(); SBAR();
    QUAD(bF01, 1, 0); SCHED0(); SBAR();
    VMCNT0(); SCHED0(); SBAR(); SCHED0();
    rdB01(1); SCHED0();
    QUAD(bF23, 1, 1); SCHED0(); SBAR();
    rdA03(1); rdB23(1); SCHED0(); SBAR(); SCHED0();
    QUAD(bF01, 0, 0); SCHED0(); SBAR();
    QUAD(bF23, 0, 1); SCHED0(); LGKM0(); SCHED0();
    rdA47(1); SCHED0();
    QUAD(bF01, 1, 0); SCHED0();
    QUAD(bF23, 1, 1);

    // epilogue: logits = 64*cos in [-64,64]; fixed shift 64 -> sum exp(logit-64)
    __syncthreads();                               // full drain; reuse LDS as red buffer
    float* red = reinterpret_cast<float*>(&lds[0][0][0]);   // [256 rows][4 wc]
    #pragma unroll
    for (int mi = 0; mi < 8; ++mi) {
        #pragma unroll
        for (int r = 0; r < 4; ++r) {
            float s = __expf(fmaf(acc[mi][0][r], 64.0f, -64.0f))
                    + __expf(fmaf(acc[mi][1][r], 64.0f, -64.0f))
                    + __expf(fmaf(acc[mi][2][r], 64.0f, -64.0f))
                    + __expf(fmaf(acc[mi][3][r], 64.0f, -64.0f));
            #pragma unroll
            for (int k = 1; k < 16; k <<= 1) s += __shfl_xor(s, k);
            if (l15 == 0) red[(wr * 128 + mi * 16 + uhi * 4 + r) * 4 + wc] = s;
        }
    }
    __syncthreads();
    if (tid < 256)
        ps[(size_t)ntile * B_ROWS + mtile * 256 + tid] =
            red[tid*4+0] + red[tid*4+1] + red[tid*4+2] + red[tid*4+3];
}

// ---------- pass 3: per-row sum of partials + exact margin/pad correction
__global__ __launch_bounds__(256) void finalize(
    const float* __restrict__ ps,
    const uint16_t* __restrict__ fb, const uint16_t* __restrict__ wb,
    const int* __restrict__ labels, float* __restrict__ row_loss)
{
    const int row = blockIdx.x;
    const int t   = threadIdx.x;      // 256
    const int lab = labels[row];

    // target cosine in f32 from the same bf16 vectors the GEMM used
    uint32_t fa = reinterpret_cast<const uint32_t*>(fb + (size_t)row * DIM)[t];
    uint32_t wa = reinterpret_cast<const uint32_t*>(wb + (size_t)lab * DIM)[t];
    float d = bf2f(fa & 0xffffu) * bf2f(wa & 0xffffu) + bf2f(fa >> 16) * bf2f(wa >> 16);
    #pragma unroll
    for (int k = 1; k < 64; k <<= 1) d += __shfl_xor(d, k);

    float s = 0.0f;
    for (int i = t; i < NT; i += 256) s += ps[(size_t)i * B_ROWS + row];
    #pragma unroll
    for (int k = 1; k < 64; k <<= 1) s += __shfl_xor(s, k);

    __shared__ float sd[4], ssm[4];
    if ((t & 63) == 0) { sd[t >> 6] = d; ssm[t >> 6] = s; }
    __syncthreads();
    if (t == 0) {
        const float dt = sd[0] + sd[1] + sd[2] + sd[3];
        float S = ssm[0] + ssm[1] + ssm[2] + ssm[3];
        const float lt = 64.0f * dt;
        // swap unmargined target term for margined one; remove pad columns (logit 0)
        S += expf(lt - 96.0f) - expf(lt - 64.0f) - (float)NPAD * expf(-64.0f);
        row_loss[row] = 64.0f + logf(S) - (lt - 32.0f);
    }
}

// ---------- pass 4: mean over rows
__global__ __launch_bounds__(256) void mean_k(const float* __restrict__ rl, float* __restrict__ out)
{
    const int t = threadIdx.x;
    float s = 0.0f;
    for (int i = t; i < B_ROWS; i += 256) s += rl[i];
    #pragma unroll
    for (int k = 1; k < 64; k <<= 1) s += __shfl_xor(s, k);
    __shared__ float r4[4];
    if ((t & 63) == 0) r4[t >> 6] = s;
    __syncthreads();
    if (t == 0) out[0] = (r4[0] + r4[1] + r4[2] + r4[3]) * (1.0f / B_ROWS);
}

extern "C" void kernel_launch(void* const* d_in, const int* in_sizes, int n_in,
                              void* d_out, int out_size, void* d_ws, size_t ws_size,
                              hipStream_t stream)
{
    const float* features = (const float*)d_in[0];
    const int*   labels   = (const int*)d_in[1];
    const float* weight   = (const float*)d_in[2];

    char* ws = (char*)d_ws;
    uint16_t* wb = (uint16_t*)ws;                                        // C_PAD * DIM bf16
    uint16_t* fb = (uint16_t*)(ws + (size_t)C_PAD * DIM * 2);            // B_ROWS * DIM bf16
    float*    psum = (float*)(ws + (size_t)C_PAD * DIM * 2 + (size_t)B_ROWS * DIM * 2);
    float*    rl = psum + (size_t)NT * B_ROWS;

    normalize_rows<<<C_PAD / 4, 256, 0, stream>>>(weight, wb, C_CLS, C_PAD);
    normalize_rows<<<B_ROWS / 4, 256, 0, stream>>>(features, fb, B_ROWS, B_ROWS);
    gemm_lse<<<NT * MT, 512, 0, stream>>>(fb, wb, psum);
    finalize<<<B_ROWS, 256, 0, stream>>>(psum, fb, wb, labels, rl);
    mean_k<<<1, 256, 0, stream>>>(rl, (float*)d_out);
}

// Round 9
// 188.776 us; speedup vs baseline: 1.2804x; 1.0066x over previous
//
#include <hip/hip_runtime.h>
#include <hip/hip_bf16.h>
#include <stdint.h>

#define B_ROWS 1024
#define DIM    512
#define C_CLS  100000
#define C_PAD  100352          // 8 XCDs * 49 ntiles * 256
#define NT     392             // C_PAD / 256
#define NT_PER_XCD 49
#define MT     4               // B_ROWS / 256
#define NPAD   (C_PAD - C_CLS) // 352 pad cols, logit 0

using f32x4  = __attribute__((ext_vector_type(4))) float;
using bf16x8 = __attribute__((ext_vector_type(8))) short;   // 8 bf16 (4 VGPRs)

#define AS1(p) ((const __attribute__((address_space(1))) uint32_t*)(p))
#define AS3(p) ((__attribute__((address_space(3))) uint32_t*)(p))
#define SBAR()   __builtin_amdgcn_s_barrier()
#define SCHED0() __builtin_amdgcn_sched_barrier(0)
#define PRIO1()  __builtin_amdgcn_s_setprio(1)
#define PRIO0()  __builtin_amdgcn_s_setprio(0)
#define LGKM0()  asm volatile("s_waitcnt lgkmcnt(0)" ::: "memory")
#define VMCNT0() asm volatile("s_waitcnt vmcnt(0)" ::: "memory")
#define VMCNT4() asm volatile("s_waitcnt vmcnt(4)" ::: "memory")
#define VMCNT8() asm volatile("s_waitcnt vmcnt(8)" ::: "memory")

static __device__ __forceinline__ float bf2f(uint32_t u) { return __uint_as_float(u << 16); }
static __device__ __forceinline__ uint32_t f2bf(float f) {
    uint32_t u = __float_as_uint(f);
    u += 0x7fffu + ((u >> 16) & 1u);          // round-to-nearest-even
    return u >> 16;
}

// ---------- pass 1: per-row L2 normalize (one wave per row), f32 -> bf16; pad rows zeroed
__global__ __launch_bounds__(256) void normalize_rows(
    const float* __restrict__ src, uint16_t* __restrict__ dst, int nvalid, int ntotal)
{
    const int row  = blockIdx.x * 4 + (threadIdx.x >> 6);
    const int lane = threadIdx.x & 63;
    if (row >= ntotal) return;
    uint4* d4 = reinterpret_cast<uint4*>(dst + (size_t)row * DIM);
    if (row >= nvalid) { d4[lane] = make_uint4(0u, 0u, 0u, 0u); return; }
    const float4* s4 = reinterpret_cast<const float4*>(src + (size_t)row * DIM);
    const float4 a = s4[lane * 2], b = s4[lane * 2 + 1];
    float ss = a.x*a.x + a.y*a.y + a.z*a.z + a.w*a.w
             + b.x*b.x + b.y*b.y + b.z*b.z + b.w*b.w;
    #pragma unroll
    for (int k = 1; k < 64; k <<= 1) ss += __shfl_xor(ss, k);
    const float inv = 1.0f / fmaxf(sqrtf(ss), 1e-12f);
    uint4 o;
    o.x = f2bf(a.x*inv) | (f2bf(a.y*inv) << 16);
    o.y = f2bf(a.z*inv) | (f2bf(a.w*inv) << 16);
    o.z = f2bf(b.x*inv) | (f2bf(b.y*inv) << 16);
    o.w = f2bf(b.z*inv) | (f2bf(b.w*inv) << 16);
    d4[lane] = o;
}

// ---------- pass 2: 256x256 bf16 MFMA; m201-template phase rhythm:
//            {reads(4-8) | 1 stage} SBAR lgkm0 [16 MFMA] SBAR, counted vmcnt(4) gates.
__global__ __launch_bounds__(512) void gemm_lse(
    const uint16_t* __restrict__ A,   // [B_ROWS][DIM]
    const uint16_t* __restrict__ W,   // [C_PAD][DIM]  (pad rows zero)
    float* __restrict__ ps)           // [NT][B_ROWS]
{
    // [buf][region h: 0=A0(rows0-127), 1=A1, 2=B0(cols0-127), 3=B1][128*64 bf16], 128 KiB
    __shared__ __align__(16) uint16_t lds[2][4][128 * 64];

    const int tid  = threadIdx.x;
    const int lane = tid & 63;
    const int wid  = tid >> 6;       // 8 waves: 2M x 4N
    const int wr   = wid >> 2;       // 0..1  (128 rows each)
    const int wc   = wid & 3;        // 0..3  (64 cols each)

    const int b     = blockIdx.x;
    const int xcd   = b & 7;
    const int j     = b >> 3;        // 0..195 within XCD
    const int ntile = xcd * NT_PER_XCD + (j >> 2);
    const int mtile = j & 3;

    const uint16_t* Abase = A + (size_t)mtile * 256 * DIM;
    const uint16_t* Bbase = W + (size_t)ntile * 256 * DIM;

    // staging: half-tile = 128 rows x 64 k = 16KB; 2 gload_lds(16B)/thread
    const int r0 = tid >> 3;
    const int us = (tid & 7) ^ (r0 & 7);      // pre-swizzled source unit (rule #21)
    const int r1 = r0 + 64;

    auto stage = [&](int kt, int h) {
        const uint16_t* src = ((h < 2) ? Abase : Bbase)
                            + (size_t)((h & 1) * 128) * DIM + kt * 64;
        uint16_t* dst = &lds[kt & 1][h][0];
        __builtin_amdgcn_global_load_lds(AS1(src + (size_t)r0 * DIM + us * 8),
                                         AS3(dst + tid * 8), 16, 0, 0);
        __builtin_amdgcn_global_load_lds(AS1(src + (size_t)r1 * DIM + us * 8),
                                         AS3(dst + (tid + 512) * 8), 16, 0, 0);
    };

    const int l15 = lane & 15;
    const int uhi = lane >> 4;
    const int ux  = lane & 7;

    bf16x8 aF[4][2], bF01[2][2], bF23[2][2];   // aF time-shared: rows 0-3 then 4-7
    f32x4 acc[8][4] = {};

    auto ldA = [&](int buf, int mi, int ks) {
        const int row  = mi * 16 + l15;
        const int unit = ((ks << 2) | uhi) ^ ux;
        return *reinterpret_cast<const bf16x8*>(&lds[buf][wr][row * 64 + unit * 8]);
    };
    auto ldB = [&](int buf, int ni, int ks) {
        const int row  = (wc & 1) * 64 + ni * 16 + l15;
        const int unit = ((ks << 2) | uhi) ^ ux;
        return *reinterpret_cast<const bf16x8*>(&lds[buf][2 + (wc >> 1)][row * 64 + unit * 8]);
    };
    auto rdA03 = [&](int buf) {
        #pragma unroll
        for (int mi = 0; mi < 4; ++mi) { aF[mi][0] = ldA(buf, mi, 0); aF[mi][1] = ldA(buf, mi, 1); }
    };
    auto rdA47 = [&](int buf) {
        #pragma unroll
        for (int mi = 0; mi < 4; ++mi) { aF[mi][0] = ldA(buf, mi + 4, 0); aF[mi][1] = ldA(buf, mi + 4, 1); }
    };
    auto rdB01 = [&](int buf) {
        #pragma unroll
        for (int ni = 0; ni < 2; ++ni) { bF01[ni][0] = ldB(buf, ni, 0); bF01[ni][1] = ldB(buf, ni, 1); }
    };
    auto rdB23 = [&](int buf) {
        #pragma unroll
        for (int ni = 0; ni < 2; ++ni) { bF23[ni][0] = ldB(buf, ni + 2, 0); bF23[ni][1] = ldB(buf, ni + 2, 1); }
    };

#define QUAD(BF, MH, NH) { PRIO1(); \
    _Pragma("unroll") for (int m2 = 0; m2 < 4; ++m2) \
    _Pragma("unroll") for (int n2 = 0; n2 < 2; ++n2) \
    _Pragma("unroll") for (int ks = 0; ks < 2; ++ks) \
        acc[(MH)*4+m2][(NH)*2+n2] = __builtin_amdgcn_mfma_f32_16x16x32_bf16( \
            aF[m2][ks], BF[n2][ks], acc[(MH)*4+m2][(NH)*2+n2], 0, 0, 0); \
    PRIO0(); }

    // prologue: kt0 H0-3, kt1 H2,H3,H0,H1 (16 loads); VMCNT8 -> kt0 fully landed,
    // outstanding = kt1 in order [H2,H3,H0,H1] (steady invariant). Pre-read bF01(kt0).
    stage(0,0); stage(0,1); stage(0,2); stage(0,3);
    stage(1,2); stage(1,3); stage(1,0); stage(1,1);
    VMCNT8(); SCHED0(); SBAR();
    rdB01(0); SCHED0();

    // steady: kt=t (buf0) at p0-3, kt+1 (buf1) at p4-7.
    // stage map: p0:c.H2 p2:c.H3 p3:c.H0 p4:c.H1 p5:d.H2 p6:d.H3 p7:d.H0+d.H1
    //   (c=kt+2 buf0, d=kt+3 buf1); VMCNT4 at p3 certifies ALL kt+1, at p7 ALL kt+2.
    #pragma unroll 1
    for (int t = 0; t < 6; t += 2) {
        // p0
        rdA03(0); stage(t+2, 2); SCHED0(); SBAR(); LGKM0(); SCHED0();
        QUAD(bF01, 0, 0); SCHED0(); SBAR();
        // p1
        rdB23(0); SCHED0(); SBAR(); LGKM0(); SCHED0();
        QUAD(bF23, 0, 1); SCHED0(); SBAR();
        // p2
        rdA47(0); stage(t+2, 3); SCHED0(); SBAR(); LGKM0(); SCHED0();
        QUAD(bF01, 1, 0); SCHED0(); SBAR();
        // p3  (gate: all kt+1 landed; pre-read bF01(kt+1) after mid-SBAR)
        VMCNT4(); SCHED0(); stage(t+2, 0); SCHED0(); SBAR(); LGKM0(); SCHED0();
        QUAD(bF23, 1, 1); SCHED0(); rdB01(1); SCHED0(); SBAR();
        // p4
        rdA03(1); stage(t+2, 1); SCHED0(); SBAR(); LGKM0(); SCHED0();
        QUAD(bF01, 0, 0); SCHED0(); SBAR();
        // p5
        rdB23(1); stage(t+3, 2); SCHED0(); SBAR(); LGKM0(); SCHED0();
        QUAD(bF23, 0, 1); SCHED0(); SBAR();
        // p6
        rdA47(1); stage(t+3, 3); SCHED0(); SBAR(); LGKM0(); SCHED0();
        QUAD(bF01, 1, 0); SCHED0(); SBAR();
        // p7  (gate: all kt+2 landed; pre-read bF01(kt+2) after mid-SBAR)
        VMCNT4(); SCHED0(); stage(t+3, 0); stage(t+3, 1); SCHED0(); SBAR(); LGKM0(); SCHED0();
        QUAD(bF23, 1, 1); SCHED0(); rdB01(0); SCHED0(); SBAR();
    }

    // tail: kt6 (buf0) p0-3, kt7 (buf1) p4-7; no stages; VMCNT0 at p3 drains kt7
    rdA03(0); SCHED0(); SBAR(); LGKM0(); SCHED0();
    QUAD(bF01, 0, 0); SCHED0(); SBAR();
    rdB23(0); SCHED0(); SBAR(); LGKM0(); SCHED0();
    QUAD(bF23, 0, 1); SCHED0(); SBAR();
    rdA47(0); SCHED0(); SBAR(); LGKM0(); SCHED0();
    QUAD(bF01, 1, 0); SCHED0(); SBAR();
    VMCNT0(); SCHED0(); SBAR(); LGKM0(); SCHED0();
    QUAD(bF23, 1, 1); SCHED0(); rdB01(1); SCHED0(); SBAR();
    rdA03(1); SCHED0(); SBAR(); LGKM0(); SCHED0();
    QUAD(bF01, 0, 0); SCHED0(); SBAR();
    rdB23(1); SCHED0(); SBAR(); LGKM0(); SCHED0();
    QUAD(bF23, 0, 1); SCHED0(); SBAR();
    rdA47(1); SCHED0(); SBAR(); LGKM0(); SCHED0();
    QUAD(bF01, 1, 0); SCHED0(); SBAR();
    LGKM0(); SCHED0();
    QUAD(bF23, 1, 1);

    // epilogue: logits = 64*cos in [-64,64]; fixed shift 64 -> sum exp(logit-64)
    __syncthreads();                               // full drain; reuse LDS as red buffer
    float* red = reinterpret_cast<float*>(&lds[0][0][0]);   // [256 rows][4 wc]
    #pragma unroll
    for (int mi = 0; mi < 8; ++mi) {
        #pragma unroll
        for (int r = 0; r < 4; ++r) {
            float s = __expf(fmaf(acc[mi][0][r], 64.0f, -64.0f))
                    + __expf(fmaf(acc[mi][1][r], 64.0f, -64.0f))
                    + __expf(fmaf(acc[mi][2][r], 64.0f, -64.0f))
                    + __expf(fmaf(acc[mi][3][r], 64.0f, -64.0f));
            #pragma unroll
            for (int k = 1; k < 16; k <<= 1) s += __shfl_xor(s, k);
            if (l15 == 0) red[(wr * 128 + mi * 16 + uhi * 4 + r) * 4 + wc] = s;
        }
    }
    __syncthreads();
    if (tid < 256)
        ps[(size_t)ntile * B_ROWS + mtile * 256 + tid] =
            red[tid*4+0] + red[tid*4+1] + red[tid*4+2] + red[tid*4+3];
}

// ---------- pass 3: per-row sum of partials + exact margin/pad correction
__global__ __launch_bounds__(256) void finalize(
    const float* __restrict__ ps,
    const uint16_t* __restrict__ fb, const uint16_t* __restrict__ wb,
    const int* __restrict__ labels, float* __restrict__ row_loss)
{
    const int row = blockIdx.x;
    const int t   = threadIdx.x;      // 256
    const int lab = labels[row];

    // target cosine in f32 from the same bf16 vectors the GEMM used
    uint32_t fa = reinterpret_cast<const uint32_t*>(fb + (size_t)row * DIM)[t];
    uint32_t wa = reinterpret_cast<const uint32_t*>(wb + (size_t)lab * DIM)[t];
    float d = bf2f(fa & 0xffffu) * bf2f(wa & 0xffffu) + bf2f(fa >> 16) * bf2f(wa >> 16);
    #pragma unroll
    for (int k = 1; k < 64; k <<= 1) d += __shfl_xor(d, k);

    float s = 0.0f;
    for (int i = t; i < NT; i += 256) s += ps[(size_t)i * B_ROWS + row];
    #pragma unroll
    for (int k = 1; k < 64; k <<= 1) s += __shfl_xor(s, k);

    __shared__ float sd[4], ssm[4];
    if ((t & 63) == 0) { sd[t >> 6] = d; ssm[t >> 6] = s; }
    __syncthreads();
    if (t == 0) {
        const float dt = sd[0] + sd[1] + sd[2] + sd[3];
        float S = ssm[0] + ssm[1] + ssm[2] + ssm[3];
        const float lt = 64.0f * dt;
        // swap unmargined target term for margined one; remove pad columns (logit 0)
        S += expf(lt - 96.0f) - expf(lt - 64.0f) - (float)NPAD * expf(-64.0f);
        row_loss[row] = 64.0f + logf(S) - (lt - 32.0f);
    }
}

// ---------- pass 4: mean over rows
__global__ __launch_bounds__(256) void mean_k(const float* __restrict__ rl, float* __restrict__ out)
{
    const int t = threadIdx.x;
    float s = 0.0f;
    for (int i = t; i < B_ROWS; i += 256) s += rl[i];
    #pragma unroll
    for (int k = 1; k < 64; k <<= 1) s += __shfl_xor(s, k);
    __shared__ float r4[4];
    if ((t & 63) == 0) r4[t >> 6] = s;
    __syncthreads();
    if (t == 0) out[0] = (r4[0] + r4[1] + r4[2] + r4[3]) * (1.0f / B_ROWS);
}

extern "C" void kernel_launch(void* const* d_in, const int* in_sizes, int n_in,
                              void* d_out, int out_size, void* d_ws, size_t ws_size,
                              hipStream_t stream)
{
    const float* features = (const float*)d_in[0];
    const int*   labels   = (const int*)d_in[1];
    const float* weight   = (const float*)d_in[2];

    char* ws = (char*)d_ws;
    uint16_t* wb = (uint16_t*)ws;                                        // C_PAD * DIM bf16
    uint16_t* fb = (uint16_t*)(ws + (size_t)C_PAD * DIM * 2);            // B_ROWS * DIM bf16
    float*    psum = (float*)(ws + (size_t)C_PAD * DIM * 2 + (size_t)B_ROWS * DIM * 2);
    float*    rl = psum + (size_t)NT * B_ROWS;

    normalize_rows<<<C_PAD / 4, 256, 0, stream>>>(weight, wb, C_CLS, C_PAD);
    normalize_rows<<<B_ROWS / 4, 256, 0, stream>>>(features, fb, B_ROWS, B_ROWS);
    gemm_lse<<<NT * MT, 512, 0, stream>>>(fb, wb, psum);
    finalize<<<B_ROWS, 256, 0, stream>>>(psum, fb, wb, labels, rl);
    mean_k<<<1, 256, 0, stream>>>(rl, (float*)d_out);
}